// Round 1
// baseline (1756.860 us; speedup 1.0000x reference)
//
#include <hip/hip_runtime.h>
#include <hip/hip_bf16.h>
#include <math.h>

#define T_TOK 8192
#define H_DIM 1024
#define I_DIM 2816
#define N_EXP 8
#define CAP_SLOTS 17408   // 2*T + 8*128 padding headroom

typedef __bf16 bf16x8 __attribute__((ext_vector_type(8)));
typedef __bf16 bf16x4 __attribute__((ext_vector_type(4)));
typedef float f32x4 __attribute__((ext_vector_type(4)));

#define M_GATE 0
#define M_UP 1
#define M_DOWN_SHARED 2
#define M_DOWN_ROUTED 3

__global__ void zero_kernel(int* __restrict__ p, int n) {
    int i = blockIdx.x * 256 + threadIdx.x;
    if (i < n) p[i] = 0;
}

__global__ void convert_x_kernel(const float* __restrict__ x, __bf16* __restrict__ xb) {
    int i = (blockIdx.x * 256 + threadIdx.x) * 4;
    float4 v = *(const float4*)(x + i);
    bf16x4 o;
    o[0] = (__bf16)v.x; o[1] = (__bf16)v.y; o[2] = (__bf16)v.z; o[3] = (__bf16)v.w;
    *(bf16x4*)(xb + i) = o;
}

// One wave per token: logits over 8 experts, softmax, top-2, renormalize.
__global__ void router_kernel(const float* __restrict__ x, const float* __restrict__ gw,
                              int* __restrict__ topi, float* __restrict__ topw,
                              int* __restrict__ counts) {
    int t = blockIdx.x * 4 + (threadIdx.x >> 6);
    int lane = threadIdx.x & 63;
    if (t >= T_TOK) return;
    const float* xr = x + (size_t)t * H_DIM;
    float s[N_EXP];
#pragma unroll
    for (int e = 0; e < N_EXP; e++) s[e] = 0.0f;
    for (int j = 0; j < H_DIM / 64; ++j) {
        float xv = xr[lane + j * 64];
#pragma unroll
        for (int e = 0; e < N_EXP; e++) s[e] += xv * gw[e * H_DIM + lane + j * 64];
    }
#pragma unroll
    for (int off = 32; off; off >>= 1) {
#pragma unroll
        for (int e = 0; e < N_EXP; e++) s[e] += __shfl_xor(s[e], off);
    }
    if (lane == 0) {
        float m = s[0];
#pragma unroll
        for (int e = 1; e < N_EXP; e++) m = fmaxf(m, s[e]);
        float p[N_EXP]; float sum = 0.0f;
#pragma unroll
        for (int e = 0; e < N_EXP; e++) { p[e] = expf(s[e] - m); sum += p[e]; }
#pragma unroll
        for (int e = 0; e < N_EXP; e++) p[e] /= sum;
        int i0 = 0;
#pragma unroll
        for (int e = 1; e < N_EXP; e++) if (p[e] > p[i0]) i0 = e;
        int i1 = (i0 == 0) ? 1 : 0;
#pragma unroll
        for (int e = 0; e < N_EXP; e++) if (e != i0 && p[e] > p[i1]) i1 = e;
        float rs = p[i0] + p[i1] + 1e-20f;
        topi[t * 2 + 0] = i0; topi[t * 2 + 1] = i1;
        topw[t * 2 + 0] = p[i0] / rs; topw[t * 2 + 1] = p[i1] / rs;
        atomicAdd(&counts[i0], 1);
        atomicAdd(&counts[i1], 1);
    }
}

__global__ void bases_kernel(const int* __restrict__ counts, int* __restrict__ bases) {
    if (threadIdx.x == 0 && blockIdx.x == 0) {
        int b = 0;
        for (int e = 0; e < N_EXP; e++) {
            bases[e] = b;
            b += ((counts[e] + 127) >> 7) << 7;   // 128-aligned regions
        }
    }
}

__global__ void build_kernel(const int* __restrict__ topi, const float* __restrict__ topw,
                             const int* __restrict__ bases, int* __restrict__ cursors,
                             int* __restrict__ token_ids, float* __restrict__ token_w) {
    int t = blockIdx.x * 256 + threadIdx.x;
    if (t >= T_TOK) return;
#pragma unroll
    for (int k = 0; k < 2; k++) {
        int e = topi[t * 2 + k];
        int slot = bases[e] + atomicAdd(&cursors[e], 1);
        token_ids[slot] = t;
        token_w[slot] = topw[t * 2 + k];
    }
}

// 128x128 tile GEMM, BK=32, 4 waves (2x2 of 64x64), double-buffered LDS (pad 40).
// A: bf16 [*, K] (gathered rows for gate/up routed). B: f32 weights [NTOT, K] (+e offset),
// converted to bf16 in-register during staging.
template<int MODE, int K, int NTOT>
__global__ __launch_bounds__(256, 2)
void gemm_moe(const __bf16* __restrict__ A, const float* __restrict__ Bw,
              __bf16* __restrict__ Hid, float* __restrict__ Out,
              const int* __restrict__ token_ids, const float* __restrict__ token_w,
              const int* __restrict__ counts, const int* __restrict__ bases,
              int Mshared) {
    const int e = blockIdx.z;
    const int m0 = blockIdx.x * 128;
    const int n0 = blockIdx.y * 128;
    int cnt, gbase;
    if (counts) {
        cnt = counts[e];
        if (m0 >= cnt) return;
        gbase = bases[e];
    } else {
        cnt = Mshared;
        gbase = 0;
        if (m0 >= cnt) return;
    }
    const float* Bwe = Bw + (size_t)e * NTOT * K;

    __shared__ __bf16 As[2][128][40];
    __shared__ __bf16 Bs[2][128][40];

    const int tid = threadIdx.x;
    const int lane = tid & 63;
    const int wid = tid >> 6;
    const int wm = wid >> 1;
    const int wn = wid & 1;

    const int sr = tid >> 1;     // staging row 0..127
    const int sh = tid & 1;      // staging half (16 elems)

    int arow;
    if (MODE == M_GATE || MODE == M_UP) {
        int slot = m0 + sr;
        arow = token_ids ? token_ids[gbase + slot] : slot;
    } else {
        arow = gbase + m0 + sr;  // hidden rows are slot-indexed
    }
    const __bf16* Arow_ptr = A + (size_t)arow * K;
    const float* Brow_ptr = Bwe + (size_t)(n0 + sr) * K;

    f32x4 acc[4][4];
    const f32x4 z4 = {0.0f, 0.0f, 0.0f, 0.0f};
#pragma unroll
    for (int i = 0; i < 4; i++)
#pragma unroll
        for (int j = 0; j < 4; j++) acc[i][j] = z4;

    constexpr int NT = K / 32;

    auto stage = [&](int buf, int kt) {
        const int k0 = kt * 32 + sh * 16;
        const __bf16* asrc = Arow_ptr + k0;
        bf16x8 a0 = ((const bf16x8*)asrc)[0];
        bf16x8 a1 = ((const bf16x8*)asrc)[1];
        *(bf16x8*)(&As[buf][sr][sh * 16]) = a0;
        *(bf16x8*)(&As[buf][sr][sh * 16 + 8]) = a1;
        const float* bsrc = Brow_ptr + k0;
        float4 b0 = ((const float4*)bsrc)[0];
        float4 b1 = ((const float4*)bsrc)[1];
        float4 b2 = ((const float4*)bsrc)[2];
        float4 b3 = ((const float4*)bsrc)[3];
        bf16x8 v0, v1;
        v0[0] = (__bf16)b0.x; v0[1] = (__bf16)b0.y; v0[2] = (__bf16)b0.z; v0[3] = (__bf16)b0.w;
        v0[4] = (__bf16)b1.x; v0[5] = (__bf16)b1.y; v0[6] = (__bf16)b1.z; v0[7] = (__bf16)b1.w;
        v1[0] = (__bf16)b2.x; v1[1] = (__bf16)b2.y; v1[2] = (__bf16)b2.z; v1[3] = (__bf16)b2.w;
        v1[4] = (__bf16)b3.x; v1[5] = (__bf16)b3.y; v1[6] = (__bf16)b3.z; v1[7] = (__bf16)b3.w;
        *(bf16x8*)(&Bs[buf][sr][sh * 16]) = v0;
        *(bf16x8*)(&Bs[buf][sr][sh * 16 + 8]) = v1;
    };

    auto compute = [&](int buf) {
        bf16x8 af[4], bfr[4];
        const int rA = wm * 64 + (lane & 15);
        const int rB = wn * 64 + (lane & 15);
        const int cK = (lane >> 4) * 8;
#pragma unroll
        for (int i = 0; i < 4; i++) af[i] = *(const bf16x8*)(&As[buf][rA + i * 16][cK]);
#pragma unroll
        for (int j = 0; j < 4; j++) bfr[j] = *(const bf16x8*)(&Bs[buf][rB + j * 16][cK]);
#pragma unroll
        for (int i = 0; i < 4; i++)
#pragma unroll
            for (int j = 0; j < 4; j++)
                acc[i][j] = __builtin_amdgcn_mfma_f32_16x16x32_bf16(af[i], bfr[j], acc[i][j], 0, 0, 0);
    };

    stage(0, 0);
    __syncthreads();
    int cur = 0;
    for (int kt = 0; kt < NT; ++kt) {
        if (kt + 1 < NT) stage(cur ^ 1, kt + 1);
        compute(cur);
        __syncthreads();
        cur ^= 1;
    }

    // Epilogue. C/D layout: col = lane&15, row = (lane>>4)*4 + reg  [m89/m91 verified]
    const int cbase = (lane & 15);
    const int rbase = (lane >> 4) * 4;
#pragma unroll
    for (int i = 0; i < 4; i++) {
#pragma unroll
        for (int j = 0; j < 4; j++) {
#pragma unroll
            for (int r = 0; r < 4; r++) {
                const int row = wm * 64 + i * 16 + rbase + r;
                const int col = wn * 64 + j * 16 + cbase;
                float v = acc[i][j][r];
                if (MODE == M_GATE) {
                    float sv = v / (1.0f + __expf(-v));
                    Hid[(size_t)(gbase + m0 + row) * NTOT + (n0 + col)] = (__bf16)sv;
                } else if (MODE == M_UP) {
                    size_t idx = (size_t)(gbase + m0 + row) * NTOT + (n0 + col);
                    float g = (float)Hid[idx];
                    Hid[idx] = (__bf16)(g * v);
                } else if (MODE == M_DOWN_SHARED) {
                    Out[(size_t)(m0 + row) * NTOT + (n0 + col)] = v;
                } else { // M_DOWN_ROUTED
                    int slot = gbase + m0 + row;
                    int tok = token_ids[slot];
                    float wgt = token_w[slot];
                    atomicAdd(&Out[(size_t)tok * NTOT + (n0 + col)], wgt * v);
                }
            }
        }
    }
}

extern "C" void kernel_launch(void* const* d_in, const int* in_sizes, int n_in,
                              void* d_out, int out_size, void* d_ws, size_t ws_size,
                              hipStream_t stream) {
    const float* x = (const float*)d_in[0];
    const float* gate_w = (const float*)d_in[1];
    const float* expert_gate = (const float*)d_in[2];
    const float* expert_up = (const float*)d_in[3];
    const float* expert_down = (const float*)d_in[4];
    const float* shared_gate = (const float*)d_in[5];
    const float* shared_up = (const float*)d_in[6];
    const float* shared_down = (const float*)d_in[7];
    float* out = (float*)d_out;

    char* w = (char*)d_ws;
    size_t off = 0;
    auto alloc = [&](size_t bytes) {
        void* p = w + off;
        off = (off + bytes + 255) & ~(size_t)255;
        return p;
    };

    __bf16* xb = (__bf16*)alloc((size_t)T_TOK * H_DIM * 2);
    int* topi = (int*)alloc((size_t)T_TOK * 2 * 4);
    float* topw = (float*)alloc((size_t)T_TOK * 2 * 4);
    // misc block (zeroed): counts[8] | cursors[8] | bases[8] | pad | token_ids[CAP] | token_w[CAP]
    const size_t misc_bytes = 128 + (size_t)CAP_SLOTS * 8;
    char* misc = (char*)alloc(misc_bytes);
    int* counts = (int*)misc;
    int* cursors = counts + 8;
    int* bases = cursors + 8;
    int* token_ids = (int*)(misc + 128);
    float* token_w = (float*)(misc + 128 + (size_t)CAP_SLOTS * 4);
    __bf16* hid_sh = (__bf16*)alloc((size_t)T_TOK * I_DIM * 2);
    __bf16* hid_rt = (__bf16*)alloc((size_t)CAP_SLOTS * I_DIM * 2);

    // 1) zero router state (+ padding slots -> token 0, weight 0)
    int zero_n = (int)(misc_bytes / 4);
    zero_kernel<<<(zero_n + 255) / 256, 256, 0, stream>>>((int*)misc, zero_n);

    // 2) router: top-2 per token + counts
    router_kernel<<<T_TOK / 4, 256, 0, stream>>>(x, gate_w, topi, topw, counts);

    // 3) 128-aligned per-expert bases
    bases_kernel<<<1, 64, 0, stream>>>(counts, bases);

    // 4) gather lists
    build_kernel<<<T_TOK / 256, 256, 0, stream>>>(topi, topw, bases, cursors, token_ids, token_w);

    // 5) x -> bf16
    convert_x_kernel<<<(T_TOK * H_DIM) / (256 * 4), 256, 0, stream>>>(x, xb);

    // 6) shared expert FFN
    gemm_moe<M_GATE, H_DIM, I_DIM><<<dim3(64, I_DIM / 128, 1), 256, 0, stream>>>(
        xb, shared_gate, hid_sh, nullptr, nullptr, nullptr, nullptr, nullptr, T_TOK);
    gemm_moe<M_UP, H_DIM, I_DIM><<<dim3(64, I_DIM / 128, 1), 256, 0, stream>>>(
        xb, shared_up, hid_sh, nullptr, nullptr, nullptr, nullptr, nullptr, T_TOK);
    gemm_moe<M_DOWN_SHARED, I_DIM, H_DIM><<<dim3(64, H_DIM / 128, 1), 256, 0, stream>>>(
        hid_sh, shared_down, nullptr, out, nullptr, nullptr, nullptr, nullptr, T_TOK);

    // 7) routed experts (gathered)
    gemm_moe<M_GATE, H_DIM, I_DIM><<<dim3(64, I_DIM / 128, N_EXP), 256, 0, stream>>>(
        xb, expert_gate, hid_rt, nullptr, token_ids, token_w, counts, bases, 0);
    gemm_moe<M_UP, H_DIM, I_DIM><<<dim3(64, I_DIM / 128, N_EXP), 256, 0, stream>>>(
        xb, expert_up, hid_rt, nullptr, token_ids, token_w, counts, bases, 0);
    gemm_moe<M_DOWN_ROUTED, I_DIM, H_DIM><<<dim3(64, H_DIM / 128, N_EXP), 256, 0, stream>>>(
        hid_rt, expert_down, nullptr, out, token_ids, token_w, counts, bases, 0);
}